// Round 14
// baseline (501.737 us; speedup 1.0000x reference)
//
#include <hip/hip_runtime.h>
#include <math.h>

#define H 128
#define STC 152   // LDS stride (shorts) for bf16 A-tiles
#define SOT 136   // LDS stride (shorts) for staged bf16 output tiles
#define SPQ 136   // LDS stride (shorts) for bf16 Spq
#define Z2S 69    // LDS stride (floats) for z2

typedef __attribute__((ext_vector_type(8))) short short8;
typedef __attribute__((ext_vector_type(4))) float f32x4;

__device__ inline unsigned short f2bf(float f) {
    unsigned int u = __float_as_uint(f);
    return (unsigned short)((u + 0x7fffu + ((u >> 16) & 1u)) >> 16);
}
__device__ inline float bflo(unsigned int v) { return __uint_as_float(v << 16); }
__device__ inline float bfhi(unsigned int v) { return __uint_as_float(v & 0xffff0000u); }
__device__ inline float bf2f(unsigned short v) { return __uint_as_float(((unsigned int)v) << 16); }

__device__ inline void fma4(float4& acc, float a, const float4 w) {
    acc.x = fmaf(a, w.x, acc.x);
    acc.y = fmaf(a, w.y, acc.y);
    acc.z = fmaf(a, w.z, acc.z);
    acc.w = fmaf(a, w.w, acc.w);
}

// ---------------- graph build ----------------

__global__ void count_kernel(const int* __restrict__ col, int E, int* __restrict__ cnt) {
    int e = blockIdx.x * blockDim.x + threadIdx.x;
    if (e < E) atomicAdd(&cnt[col[e]], 1);
}

__global__ void scan_sum_kernel(const int* __restrict__ cnt, int N, int* __restrict__ bsum) {
    int b = blockIdx.x, t = threadIdx.x;
    int base = b * 1024 + t * 4;
    int s = 0;
#pragma unroll
    for (int g = 0; g < 4; ++g) {
        int i = base + g;
        if (i < N) s += cnt[i];
    }
    for (int off = 32; off >= 1; off >>= 1) s += __shfl_down(s, off, 64);
    __shared__ int ws[4];
    if ((t & 63) == 0) ws[t >> 6] = s;
    __syncthreads();
    if (t == 0) bsum[b] = ws[0] + ws[1] + ws[2] + ws[3];
}

__global__ void scan_offsets_kernel(const int* __restrict__ bsum, int nb,
                                    int* __restrict__ boff, int* __restrict__ col_start, int N) {
    int lane = threadIdx.x;
    int v = (lane < nb) ? bsum[lane] : 0;
    int incl = v;
    for (int off = 1; off < 64; off <<= 1) {
        int u = __shfl_up(incl, off, 64);
        if (lane >= off) incl += u;
    }
    if (lane < nb) boff[lane] = incl - v;
    if (lane == 63) col_start[N] = incl;
}

__global__ void scan_write_kernel(const int* __restrict__ cnt, int N, const int* __restrict__ boff,
                                  int* __restrict__ col_start, int* __restrict__ cursor,
                                  float* __restrict__ dinv) {
    int b = blockIdx.x, t = threadIdx.x;
    int lane = t & 63, wv = t >> 6;
    int base = b * 1024 + t * 4;
    int c[4];
    int s = 0;
#pragma unroll
    for (int g = 0; g < 4; ++g) {
        int i = base + g;
        c[g] = (i < N) ? cnt[i] : 0;
        s += c[g];
    }
    int incl = s;
    for (int off = 1; off < 64; off <<= 1) {
        int u = __shfl_up(incl, off, 64);
        if (lane >= off) incl += u;
    }
    __shared__ int ws[4];
    if (lane == 63) ws[wv] = incl;
    __syncthreads();
    int run = boff[b] + incl - s;
    for (int w = 0; w < wv; ++w) run += ws[w];
#pragma unroll
    for (int g = 0; g < 4; ++g) {
        int i = base + g;
        if (i < N) {
            col_start[i] = run;
            cursor[i] = run;
            dinv[i] = rsqrtf((float)(c[g] + 1));
            run += c[g];
        }
    }
}

__global__ void scatter_kernel(const int* __restrict__ row, const int* __restrict__ col, int E,
                               int* __restrict__ cursor, int* __restrict__ csc_src,
                               int2* __restrict__ csc_ec) {
    int e = blockIdx.x * blockDim.x + threadIdx.x;
    if (e < E) {
        int c = col[e];
        int p = atomicAdd(&cursor[c], 1);
        csc_src[p] = row[e];
        csc_ec[p] = make_int2(e, c);
    }
}

// ---------------- classifier weight prep ----------------

__global__ void weff_kernel(const float* __restrict__ We2, const float* __restrict__ Wc1,
                            float* __restrict__ Weff) {
    int idx = blockIdx.x * blockDim.x + threadIdx.x;
    int k = idx >> 7, c = idx & 127;
    float acc = 0.f;
    for (int j = 0; j < 128; ++j)
        acc = fmaf(We2[k * 128 + j], Wc1[(256 + j) * 128 + c], acc);
    Weff[idx] = acc;
}

__global__ void bc1p_kernel(const float* __restrict__ bc1, const float* __restrict__ be2,
                            const float* __restrict__ Wc1, float* __restrict__ bc1p) {
    int c = threadIdx.x;
    float acc = bc1[c];
    for (int j = 0; j < 128; ++j)
        acc = fmaf(be2[j], Wc1[(256 + j) * 128 + c], acc);
    bc1p[c] = acc;
}

// one kernel for all weight packing (46 blocks x 256)
__global__ void pack_all_kernel(const float* __restrict__ Wc1, const float* __restrict__ Weff,
                                const float* __restrict__ W2, const float* __restrict__ W3,
                                const float* __restrict__ Wc2,
                                const float* __restrict__ We1, const float* __restrict__ be1,
                                unsigned short* __restrict__ BpA, unsigned short* __restrict__ BpB,
                                unsigned short* __restrict__ BpU, unsigned short* __restrict__ BpW2,
                                unsigned short* __restrict__ BpW3, unsigned short* __restrict__ Bp2,
                                unsigned short* __restrict__ BpE) {
    int b = blockIdx.x;
    if (b < 40) {
        // packg: 128x128 -> 16x16x32 B-fragments [s<4][nt<8][lane][8]
        const float* src;
        unsigned short* dst;
        int which = b >> 3;
        if (which == 0)      { src = Wc1;          dst = BpA; }
        else if (which == 1) { src = Wc1 + 16384;  dst = BpB; }
        else if (which == 2) { src = Weff;         dst = BpU; }
        else if (which == 3) { src = W2;           dst = BpW2; }
        else                 { src = W3;           dst = BpW3; }
        int idx = (b & 7) * 256 + threadIdx.x;  // 0..2047
        int s = idx >> 9, nt = (idx >> 6) & 7, lane = idx & 63;
        int quad = lane >> 4, lm = lane & 15;
        int n = nt * 16 + lm, k0 = s * 32 + quad * 8;
        unsigned int p[4];
#pragma unroll
        for (int g = 0; g < 4; ++g) {
            p[g] = (unsigned int)f2bf(src[(k0 + 2 * g) * 128 + n]) |
                   ((unsigned int)f2bf(src[(k0 + 2 * g + 1) * 128 + n]) << 16);
        }
        *(uint4*)&dst[(size_t)idx * 8] = make_uint4(p[0], p[1], p[2], p[3]);
    } else if (b < 44) {
        // pack2: Wc2 128x64 -> [s<4][nt<4][lane][8]
        int idx = (b - 40) * 256 + threadIdx.x;  // 0..1023
        int s = idx >> 8, nt = (idx >> 6) & 3, lane = idx & 63;
        int quad = lane >> 4, lm = lane & 15;
        int n = nt * 16 + lm, k0 = s * 32 + quad * 8;
        unsigned int p[4];
#pragma unroll
        for (int g = 0; g < 4; ++g) {
            p[g] = (unsigned int)f2bf(Wc2[(k0 + 2 * g) * 64 + n]) |
                   ((unsigned int)f2bf(Wc2[(k0 + 2 * g + 1) * 64 + n]) << 16);
        }
        *(uint4*)&Bp2[(size_t)idx * 8] = make_uint4(p[0], p[1], p[2], p[3]);
    } else {
        // packwe1: We1_ext rows 0..3 = We1, row 4 = be1, rest 0
        int idx = (b - 44) * 256 + threadIdx.x;  // 0..511
        if (idx < 512) {
            int nt = idx >> 6, lane = idx & 63;
            int quad = lane >> 4, lm = lane & 15;
            int n = nt * 16 + lm, k0 = quad * 8;
            unsigned int p[4];
#pragma unroll
            for (int g = 0; g < 4; ++g) {
                int r0 = k0 + 2 * g, r1 = r0 + 1;
                float v0 = (r0 < 4) ? We1[r0 * 128 + n] : ((r0 == 4) ? be1[n] : 0.f);
                float v1 = (r1 < 4) ? We1[r1 * 128 + n] : ((r1 == 4) ? be1[n] : 0.f);
                p[g] = (unsigned int)f2bf(v0) | ((unsigned int)f2bf(v1) << 16);
            }
            *(uint4*)&BpE[(size_t)idx * 8] = make_uint4(p[0], p[1], p[2], p[3]);
        }
    }
}

// ---------------- fused GCN layers ----------------

// layer 1: aggregate raw x (8 feats) + W1 transform -> h1d (dinv-prescaled bf16)
__global__ __launch_bounds__(256) void layer1_kernel(
    const float* __restrict__ x, const int* __restrict__ col_start,
    const int* __restrict__ csc_src, const float* __restrict__ dinv,
    const float* __restrict__ W1, const float* __restrict__ b1,
    unsigned int* __restrict__ out, int N) {
    __shared__ float ax_s[64][8];
    int tid = threadIdx.x, wv = tid >> 6, lane = tid & 63;
    int i0 = blockIdx.x * 64;
    int f = lane & 7, j = lane >> 3;
    for (int k = 0; k < 16; ++k) {
        int i = i0 + wv * 16 + k;
        if (i < N) {
            int s0 = col_start[i], s1 = col_start[i + 1];
            float acc = 0.f;
            int p = s0 + j;
            for (; p + 8 < s1; p += 16) {
                int sa = csc_src[p], sb = csc_src[p + 8];
                acc += dinv[sa] * x[sa * 8 + f] + dinv[sb] * x[sb * 8 + f];
            }
            if (p < s1) {
                int s = csc_src[p];
                acc = fmaf(dinv[s], x[s * 8 + f], acc);
            }
            acc += __shfl_xor(acc, 8, 64);
            acc += __shfl_xor(acc, 16, 64);
            acc += __shfl_xor(acc, 32, 64);
            if (j == 0) {
                float di = dinv[i];
                ax_s[wv * 16 + k][f] = fmaf(di, acc, di * di * x[i * 8 + f]);
            }
        }
    }
    __syncthreads();
    // transform K=8 -> 128 cols (bf16 pairs), dinv prescale
    for (int u = tid; u < 4096; u += 256) {
        int k = u >> 6, jp = u & 63;
        int node = i0 + k;
        if (node >= N) continue;
        const float* ar = ax_s[k];
        float sc = dinv[node];
        int j0 = jp * 2;
        float a0 = b1[j0], a1 = b1[j0 + 1];
#pragma unroll
        for (int kk = 0; kk < 8; ++kk) {
            float av = ar[kk];
            a0 = fmaf(av, W1[kk * 128 + j0], a0);
            a1 = fmaf(av, W1[kk * 128 + j0 + 1], a1);
        }
        out[(size_t)node * 64 + jp] = (unsigned int)f2bf(sc * fmaxf(a0, 0.f)) |
                                      ((unsigned int)f2bf(sc * fmaxf(a1, 0.f)) << 16);
    }
}

// layer 2: aggregate h1d + W2 MFMA transform -> h2d (dinv-prescaled bf16). 512 thr, 8 waves.
__global__ __launch_bounds__(512) void layer2_kernel(
    const unsigned int* __restrict__ hd, const int* __restrict__ col_start,
    const int* __restrict__ csc_src, const float* __restrict__ dinv,
    const unsigned short* __restrict__ Bp, const float* __restrict__ b,
    const float* __restrict__ scale, unsigned short* __restrict__ out, int N) {
    __shared__ __align__(16) unsigned short At[64 * STC];
    int tid = threadIdx.x, wv = tid >> 6, lane = tid & 63;
    int lm = lane & 15, quad = lane >> 4;
    int i0 = blockIdx.x * 64;

    // B-frags for nt = wv (hoisted; overlaps agg latency)
    short8 bs[4];
#pragma unroll
    for (int s = 0; s < 4; ++s)
        bs[s] = *(const short8*)&Bp[((size_t)(s * 8 + wv) * 64 + lane) * 8];
    float bv = b[wv * 16 + lm];

    unsigned int* At32 = (unsigned int*)At;
    for (int k = 0; k < 8; ++k) {
        int i = i0 + wv * 8 + k;
        int ii = (i < N) ? i : N - 1;
        int s0 = col_start[ii], s1 = col_start[ii + 1];
        float ax = 0.f, ay = 0.f;
        int p = s0;
        for (; p + 16 <= s1; p += 16) {
            unsigned int v[16];
#pragma unroll
            for (int t = 0; t < 16; ++t) v[t] = hd[(size_t)csc_src[p + t] * 64 + lane];
#pragma unroll
            for (int t = 0; t < 16; ++t) { ax += bflo(v[t]); ay += bfhi(v[t]); }
        }
        for (; p + 4 <= s1; p += 4) {
            unsigned int v0 = hd[(size_t)csc_src[p + 0] * 64 + lane];
            unsigned int v1 = hd[(size_t)csc_src[p + 1] * 64 + lane];
            unsigned int v2 = hd[(size_t)csc_src[p + 2] * 64 + lane];
            unsigned int v3 = hd[(size_t)csc_src[p + 3] * 64 + lane];
            ax += bflo(v0) + bflo(v1) + bflo(v2) + bflo(v3);
            ay += bfhi(v0) + bfhi(v1) + bfhi(v2) + bfhi(v3);
        }
        for (; p < s1; ++p) {
            unsigned int v = hd[(size_t)csc_src[p] * 64 + lane];
            ax += bflo(v); ay += bfhi(v);
        }
        float di = dinv[ii];
        unsigned int vs = hd[(size_t)ii * 64 + lane];
        float rx = di * (ax + bflo(vs));
        float ry = di * (ay + bfhi(vs));
        At32[(wv * 8 + k) * 76 + lane] = (unsigned int)f2bf(rx) | ((unsigned int)f2bf(ry) << 16);
    }
    __syncthreads();

    // MFMA: wave wv owns n-tile wv
    f32x4 acc[4];
    for (int m = 0; m < 4; ++m)
        for (int r = 0; r < 4; ++r) acc[m][r] = bv;
#pragma unroll
    for (int s = 0; s < 4; ++s) {
#pragma unroll
        for (int m = 0; m < 4; ++m) {
            short8 afr = *(const short8*)&At[(m * 16 + lm) * STC + s * 32 + quad * 8];
            acc[m] = __builtin_amdgcn_mfma_f32_16x16x32_bf16(afr, bs[s], acc[m], 0, 0, 0);
        }
    }
    __syncthreads();  // all At reads done -> overlay staging [64][SOT]
    for (int m = 0; m < 4; ++m)
        for (int r = 0; r < 4; ++r) {
            int rw = m * 16 + quad * 4 + r;
            int node = i0 + rw; if (node >= N) node = N - 1;
            float sc = scale ? scale[node] : 1.f;
            At[rw * SOT + wv * 16 + lm] = f2bf(sc * fmaxf(acc[m][r], 0.f));
        }
    __syncthreads();
    for (int u = tid; u < 1024; u += 512) {
        int i = u >> 4, l = u & 15;
        int node = i0 + i;
        if (node < N)
            *(uint4*)&out[(size_t)node * 128 + l * 8] = *(uint4*)&At[i * SOT + l * 8];
    }
}

// layer 3: aggregate h2d + W3 + Wc1a/Wc1b -> P, Q (bf16). 512 thr, 8 waves.
__global__ __launch_bounds__(512) void layer3_kernel(
    const unsigned int* __restrict__ hd, const int* __restrict__ col_start,
    const int* __restrict__ csc_src, const float* __restrict__ dinv,
    const unsigned short* __restrict__ BpW3, const float* __restrict__ b3,
    const unsigned short* __restrict__ BpA, const unsigned short* __restrict__ BpB,
    const float* __restrict__ bc1p,
    unsigned short* __restrict__ P, unsigned short* __restrict__ Q, int N) {
    __shared__ __align__(16) unsigned short At[64 * STC];  // agg rows; later staging [64][SOT]
    __shared__ __align__(16) unsigned short Hs[64 * SOT];  // h3 rows
    int tid = threadIdx.x, wv = tid >> 6, lane = tid & 63;
    int lm = lane & 15, quad = lane >> 4;
    int i0 = blockIdx.x * 64;

    short8 bw3[4];
#pragma unroll
    for (int s = 0; s < 4; ++s)
        bw3[s] = *(const short8*)&BpW3[((size_t)(s * 8 + wv) * 64 + lane) * 8];
    float bv3 = b3[wv * 16 + lm];

    unsigned int* At32 = (unsigned int*)At;
    for (int k = 0; k < 8; ++k) {
        int i = i0 + wv * 8 + k;
        int ii = (i < N) ? i : N - 1;
        int s0 = col_start[ii], s1 = col_start[ii + 1];
        float ax = 0.f, ay = 0.f;
        int p = s0;
        for (; p + 16 <= s1; p += 16) {
            unsigned int v[16];
#pragma unroll
            for (int t = 0; t < 16; ++t) v[t] = hd[(size_t)csc_src[p + t] * 64 + lane];
#pragma unroll
            for (int t = 0; t < 16; ++t) { ax += bflo(v[t]); ay += bfhi(v[t]); }
        }
        for (; p + 4 <= s1; p += 4) {
            unsigned int v0 = hd[(size_t)csc_src[p + 0] * 64 + lane];
            unsigned int v1 = hd[(size_t)csc_src[p + 1] * 64 + lane];
            unsigned int v2 = hd[(size_t)csc_src[p + 2] * 64 + lane];
            unsigned int v3 = hd[(size_t)csc_src[p + 3] * 64 + lane];
            ax += bflo(v0) + bflo(v1) + bflo(v2) + bflo(v3);
            ay += bfhi(v0) + bfhi(v1) + bfhi(v2) + bfhi(v3);
        }
        for (; p < s1; ++p) {
            unsigned int v = hd[(size_t)csc_src[p] * 64 + lane];
            ax += bflo(v); ay += bfhi(v);
        }
        float di = dinv[ii];
        unsigned int vs = hd[(size_t)ii * 64 + lane];
        float rx = di * (ax + bflo(vs));
        float ry = di * (ay + bfhi(vs));
        At32[(wv * 8 + k) * 76 + lane] = (unsigned int)f2bf(rx) | ((unsigned int)f2bf(ry) << 16);
    }
    __syncthreads();

    // W3 transform: wave wv owns n-tile wv; h3 -> Hs (A-layout rows)
    {
        f32x4 acc[4];
        for (int m = 0; m < 4; ++m)
            for (int r = 0; r < 4; ++r) acc[m][r] = bv3;
#pragma unroll
        for (int s = 0; s < 4; ++s) {
#pragma unroll
            for (int m = 0; m < 4; ++m) {
                short8 afr = *(const short8*)&At[(m * 16 + lm) * STC + s * 32 + quad * 8];
                acc[m] = __builtin_amdgcn_mfma_f32_16x16x32_bf16(afr, bw3[s], acc[m], 0, 0, 0);
            }
        }
        for (int m = 0; m < 4; ++m)
            for (int r = 0; r < 4; ++r) {
                int rw = m * 16 + quad * 4 + r;
                Hs[rw * SOT + wv * 16 + lm] = f2bf(fmaxf(acc[m][r], 0.f));
            }
    }
    __syncthreads();

    // Wc1 halves: wave wv -> (sel = wv>>2: 0=P 1=Q; g = wv&3 -> n-tiles 2g, 2g+1)
    int sel = wv >> 2, g = wv & 3;
    int nt0 = 2 * g, nt1 = 2 * g + 1;
    const unsigned short* Bp = sel ? BpB : BpA;
    f32x4 a0[4], a1[4];
    {
        float bv0 = sel ? 0.f : bc1p[nt0 * 16 + lm];
        float bv1 = sel ? 0.f : bc1p[nt1 * 16 + lm];
        for (int m = 0; m < 4; ++m)
            for (int r = 0; r < 4; ++r) { a0[m][r] = bv0; a1[m][r] = bv1; }
    }
#pragma unroll
    for (int s = 0; s < 4; ++s) {
        short8 b0 = *(const short8*)&Bp[((size_t)(s * 8 + nt0) * 64 + lane) * 8];
        short8 b1 = *(const short8*)&Bp[((size_t)(s * 8 + nt1) * 64 + lane) * 8];
#pragma unroll
        for (int m = 0; m < 4; ++m) {
            short8 afr = *(const short8*)&Hs[(m * 16 + lm) * SOT + s * 32 + quad * 8];
            a0[m] = __builtin_amdgcn_mfma_f32_16x16x32_bf16(afr, b0, a0[m], 0, 0, 0);
            a1[m] = __builtin_amdgcn_mfma_f32_16x16x32_bf16(afr, b1, a1[m], 0, 0, 0);
        }
    }
    __syncthreads();  // At reads long done -> reuse as staging St[64][SOT]
    unsigned short* St = At;

    if (sel == 0) {
        for (int m = 0; m < 4; ++m)
            for (int r = 0; r < 4; ++r) {
                int rw = m * 16 + quad * 4 + r;
                St[rw * SOT + nt0 * 16 + lm] = f2bf(a0[m][r]);
                St[rw * SOT + nt1 * 16 + lm] = f2bf(a1[m][r]);
            }
    }
    __syncthreads();
    for (int u = tid; u < 1024; u += 512) {
        int i = u >> 4, l = u & 15;
        int node = i0 + i;
        if (node < N)
            *(uint4*)&P[(size_t)node * 128 + l * 8] = *(uint4*)&St[i * SOT + l * 8];
    }
    __syncthreads();
    if (sel == 1) {
        for (int m = 0; m < 4; ++m)
            for (int r = 0; r < 4; ++r) {
                int rw = m * 16 + quad * 4 + r;
                St[rw * SOT + nt0 * 16 + lm] = f2bf(a0[m][r]);
                St[rw * SOT + nt1 * 16 + lm] = f2bf(a1[m][r]);
            }
    }
    __syncthreads();
    for (int u = tid; u < 1024; u += 512) {
        int i = u >> 4, l = u & 15;
        int node = i0 + i;
        if (node < N)
            *(uint4*)&Q[(size_t)node * 128 + l * 8] = *(uint4*)&St[i * SOT + l * 8];
    }
}

// ---------------- fused classifier, all-MFMA (unchanged from r12) ----------------

__global__ __launch_bounds__(256, 4) void classifier_mfma2(
    const int* __restrict__ csc_src, const int2* __restrict__ csc_ec,
    const float* __restrict__ ea, const unsigned short* __restrict__ BpE,
    const unsigned short* __restrict__ P, const unsigned short* __restrict__ Q,
    const unsigned short* __restrict__ BpU, const unsigned short* __restrict__ Bp2,
    const float* __restrict__ bc2, const float* __restrict__ Wc3, const float* __restrict__ bc3,
    float* __restrict__ out, int E) {
    __shared__ __align__(16) unsigned char smem[37888];
    unsigned short* SpqB = (unsigned short*)smem;         // [64][SPQ] bf16
    float* z2 = (float*)smem;                             // [64][Z2S] fp32 (overlay)
    unsigned short* At = (unsigned short*)(smem + 17664); // [64][STC] bf16 (t, then z1)
    unsigned short* z1 = At;                              // overlay
    float* part = (float*)(smem + 17664);                 // [4][64] (overlay)
    int* sS = (int*)(smem + 37120);
    int* eS = sS + 64;
    int* cS = eS + 64;

    int tid = threadIdx.x;
    int lane = tid & 63, w = tid >> 6, lm = lane & 15, quad = lane >> 4;
    int e0 = blockIdx.x * 64;

    short8 bE0 = *(const short8*)&BpE[((size_t)(2 * w) * 64 + lane) * 8];
    short8 bE1 = *(const short8*)&BpE[((size_t)(2 * w + 1) * 64 + lane) * 8];
    short8 b0s[4], b1s[4], b2s[4];
#pragma unroll
    for (int s = 0; s < 4; ++s) {
        b0s[s] = *(const short8*)&BpU[((size_t)(s * 8 + 2 * w) * 64 + lane) * 8];
        b1s[s] = *(const short8*)&BpU[((size_t)(s * 8 + 2 * w + 1) * 64 + lane) * 8];
        b2s[s] = *(const short8*)&Bp2[((size_t)(s * 4 + w) * 64 + lane) * 8];
    }
    float bv2 = bc2[w * 16 + lm];

    if (tid < 64) {
        int p = e0 + tid; if (p >= E) p = E - 1;
        sS[tid] = csc_src[p];
        int2 ec = csc_ec[p];
        eS[tid] = ec.x; cS[tid] = ec.y;
    }
    __syncthreads();

    {
        const uint4* P4 = (const uint4*)P;
        const uint4* Q4 = (const uint4*)Q;
        int l = tid & 15;
#pragma unroll
        for (int j = 0; j < 4; ++j) {
            int i = (tid >> 4) + 16 * j;
            uint4 pv = P4[(size_t)sS[i] * 16 + l];
            uint4 qv = Q4[(size_t)cS[i] * 16 + l];
            unsigned int o0 = (unsigned int)f2bf(bflo(pv.x) + bflo(qv.x)) |
                              ((unsigned int)f2bf(bfhi(pv.x) + bfhi(qv.x)) << 16);
            unsigned int o1 = (unsigned int)f2bf(bflo(pv.y) + bflo(qv.y)) |
                              ((unsigned int)f2bf(bfhi(pv.y) + bfhi(qv.y)) << 16);
            unsigned int o2 = (unsigned int)f2bf(bflo(pv.z) + bflo(qv.z)) |
                              ((unsigned int)f2bf(bfhi(pv.z) + bfhi(qv.z)) << 16);
            unsigned int o3 = (unsigned int)f2bf(bflo(pv.w) + bflo(qv.w)) |
                              ((unsigned int)f2bf(bfhi(pv.w) + bfhi(qv.w)) << 16);
            *(uint4*)&SpqB[i * SPQ + l * 8] = make_uint4(o0, o1, o2, o3);
        }
    }

    short8 eaf[4];
#pragma unroll
    for (int m = 0; m < 4; ++m) eaf[m] = (short8){0, 0, 0, 0, 0, 0, 0, 0};
    if (quad == 0) {
#pragma unroll
        for (int m = 0; m < 4; ++m) {
            int ed = eS[m * 16 + lm];
            float4 a = ((const float4*)ea)[ed];
            eaf[m][0] = (short)f2bf(a.x);
            eaf[m][1] = (short)f2bf(a.y);
            eaf[m][2] = (short)f2bf(a.z);
            eaf[m][3] = (short)f2bf(a.w);
            eaf[m][4] = (short)0x3F80;  // 1.0 bf16
        }
    }

    {
        f32x4 zacc = {0.f, 0.f, 0.f, 0.f};
#pragma unroll
        for (int m = 0; m < 4; ++m) {
            f32x4 t0 = __builtin_amdgcn_mfma_f32_16x16x32_bf16(eaf[m], bE0, zacc, 0, 0, 0);
            f32x4 t1 = __builtin_amdgcn_mfma_f32_16x16x32_bf16(eaf[m], bE1, zacc, 0, 0, 0);
#pragma unroll
            for (int r = 0; r < 4; ++r) {
                int rw = m * 16 + quad * 4 + r;
                At[rw * STC + 32 * w + lm]      = f2bf(fmaxf(t0[r], 0.f));
                At[rw * STC + 32 * w + 16 + lm] = f2bf(fmaxf(t1[r], 0.f));
            }
        }
    }
    __syncthreads();

    f32x4 acc0[4], acc1[4];
    for (int m = 0; m < 4; ++m)
        for (int r = 0; r < 4; ++r) { acc0[m][r] = 0.f; acc1[m][r] = 0.f; }
#pragma unroll
    for (int s = 0; s < 4; ++s) {
#pragma unroll
        for (int m = 0; m < 4; ++m) {
            short8 afr = *(const short8*)&At[(m * 16 + lm) * STC + s * 32 + quad * 8];
            acc0[m] = __builtin_amdgcn_mfma_f32_16x16x32_bf16(afr, b0s[s], acc0[m], 0, 0, 0);
            acc1[m] = __builtin_amdgcn_mfma_f32_16x16x32_bf16(afr, b1s[s], acc1[m], 0, 0, 0);
        }
    }
    for (int m = 0; m < 4; ++m)
        for (int r = 0; r < 4; ++r) {
            int rw = m * 16 + quad * 4 + r;
            acc0[m][r] = fmaxf(acc0[m][r] + bf2f(SpqB[rw * SPQ + 32 * w + lm]), 0.f);
            acc1[m][r] = fmaxf(acc1[m][r] + bf2f(SpqB[rw * SPQ + 32 * w + 16 + lm]), 0.f);
        }
    __syncthreads();
    for (int m = 0; m < 4; ++m)
        for (int r = 0; r < 4; ++r) {
            int rw = m * 16 + quad * 4 + r;
            z1[rw * STC + 32 * w + lm]      = f2bf(acc0[m][r]);
            z1[rw * STC + 32 * w + 16 + lm] = f2bf(acc1[m][r]);
        }
    __syncthreads();

    {
        f32x4 acc2[4];
        for (int m = 0; m < 4; ++m)
            for (int r = 0; r < 4; ++r) acc2[m][r] = bv2;
#pragma unroll
        for (int s = 0; s < 4; ++s) {
#pragma unroll
            for (int m = 0; m < 4; ++m) {
                short8 afr = *(const short8*)&z1[(m * 16 + lm) * STC + s * 32 + quad * 8];
                acc2[m] = __builtin_amdgcn_mfma_f32_16x16x32_bf16(afr, b2s[s], acc2[m], 0, 0, 0);
            }
        }
        for (int m = 0; m < 4; ++m)
            for (int r = 0; r < 4; ++r)
                z2[(m * 16 + quad * 4 + r) * Z2S + w * 16 + lm] = fmaxf(acc2[m][r], 0.f);
    }
    __syncthreads();

    {
        int e = tid & 63, q = tid >> 6;
        int c = q & 1, hf = q >> 1;
        const float* zr = z2 + e * Z2S + hf * 32;
        const float* wc = Wc3 + hf * 64 + c;
        float acc = 0.f;
#pragma unroll 8
        for (int kk = 0; kk < 32; ++kk)
            acc = fmaf(zr[kk], wc[2 * kk], acc);
        part[q * 64 + e] = acc;
    }
    __syncthreads();
    if (tid < 64) {
        int p = e0 + tid;
        if (p < E) {
            float l0 = bc3[0] + part[tid] + part[128 + tid];
            float l1 = bc3[1] + part[64 + tid] + part[192 + tid];
            float m = fmaxf(l0, l1);
            float lse = m + logf(expf(l0 - m) + expf(l1 - m));
            ((float2*)out)[eS[tid]] = make_float2(l0 - lse, l1 - lse);
        }
    }
}

// ---------------- launch ----------------

extern "C" void kernel_launch(void* const* d_in, const int* in_sizes, int n_in,
                              void* d_out, int out_size, void* d_ws, size_t ws_size,
                              hipStream_t stream) {
    const float* x   = (const float*)d_in[0];
    const int*   ei  = (const int*)d_in[1];
    const float* ea  = (const float*)d_in[2];
    const float* W1  = (const float*)d_in[3];
    const float* b1  = (const float*)d_in[4];
    const float* W2  = (const float*)d_in[5];
    const float* b2  = (const float*)d_in[6];
    const float* W3  = (const float*)d_in[7];
    const float* b3  = (const float*)d_in[8];
    const float* We1 = (const float*)d_in[9];
    const float* be1 = (const float*)d_in[10];
    const float* We2 = (const float*)d_in[11];
    const float* be2 = (const float*)d_in[12];
    const float* Wc1 = (const float*)d_in[13];
    const float* bc1 = (const float*)d_in[14];
    const float* Wc2 = (const float*)d_in[15];
    const float* bc2 = (const float*)d_in[16];
    const float* Wc3 = (const float*)d_in[17];
    const float* bc3 = (const float*)d_in[18];
    float* out = (float*)d_out;

    int N = in_sizes[0] / 8;
    int E = in_sizes[1] / 2;
    const int* row = ei;
    const int* col = ei + E;
    int NB = (N + 1023) / 1024;
    int ntiles = (E + 63) / 64;
    int nodetiles = (N + 63) / 64;

    char* w = (char*)d_ws;
    auto alloc = [&](size_t bytes) { void* p = (void*)w; w += (bytes + 255) & ~(size_t)255; return p; };
    int*   cnt       = (int*)alloc((size_t)N * 4);
    int*   col_start = (int*)alloc((size_t)(N + 1) * 4);
    int*   cursor    = (int*)alloc((size_t)N * 4);
    int*   csc_src   = (int*)alloc((size_t)E * 4);
    int2*  csc_ec    = (int2*)alloc((size_t)E * 8);
    float* dinv      = (float*)alloc((size_t)N * 4);
    int*   bsum      = (int*)alloc(64 * 4);
    int*   boff      = (int*)alloc(64 * 4);
    float* Weff      = (float*)alloc(128 * 128 * 4);
    float* bc1p      = (float*)alloc(128 * 4);
    unsigned short* BpA  = (unsigned short*)alloc(32768);
    unsigned short* BpB  = (unsigned short*)alloc(32768);
    unsigned short* BpU  = (unsigned short*)alloc(32768);
    unsigned short* BpW2 = (unsigned short*)alloc(32768);
    unsigned short* BpW3 = (unsigned short*)alloc(32768);
    unsigned short* Bp2  = (unsigned short*)alloc(16384);
    unsigned short* BpE  = (unsigned short*)alloc(8192);
    unsigned short* bufA = (unsigned short*)alloc((size_t)N * H * 2);
    unsigned short* bufB = (unsigned short*)alloc((size_t)N * H * 2);
    unsigned short* Pm   = (unsigned short*)alloc((size_t)N * H * 2);
    unsigned short* Qm   = (unsigned short*)alloc((size_t)N * H * 2);

    // graph build (CSC with eid+col)
    hipMemsetAsync(cnt, 0, (size_t)N * 4, stream);
    count_kernel<<<(E + 255) / 256, 256, 0, stream>>>(col, E, cnt);
    scan_sum_kernel<<<NB, 256, 0, stream>>>(cnt, N, bsum);
    scan_offsets_kernel<<<1, 64, 0, stream>>>(bsum, NB, boff, col_start, N);
    scan_write_kernel<<<NB, 256, 0, stream>>>(cnt, N, boff, col_start, cursor, dinv);
    scatter_kernel<<<(E + 255) / 256, 256, 0, stream>>>(row, col, E, cursor, csc_src, csc_ec);

    // weight prep
    weff_kernel<<<64, 256, 0, stream>>>(We2, Wc1, Weff);
    bc1p_kernel<<<1, 128, 0, stream>>>(bc1, be2, Wc1, bc1p);
    pack_all_kernel<<<46, 256, 0, stream>>>(Wc1, Weff, W2, W3, Wc2, We1, be1,
                                            BpA, BpB, BpU, BpW2, BpW3, Bp2, BpE);

    // fused GCN layers (dinv-prescaled bf16 features)
    layer1_kernel<<<nodetiles, 256, 0, stream>>>(x, col_start, csc_src, dinv, W1, b1,
                                                 (unsigned int*)bufA, N);                  // h1d
    layer2_kernel<<<nodetiles, 512, 0, stream>>>((const unsigned int*)bufA, col_start, csc_src,
                                                 dinv, BpW2, b2, dinv, bufB, N);           // h2d
    layer3_kernel<<<nodetiles, 512, 0, stream>>>((const unsigned int*)bufB, col_start, csc_src,
                                                 dinv, BpW3, b3, BpA, BpB, bc1p, Pm, Qm, N);

    // fused all-MFMA classifier in CSC order
    classifier_mfma2<<<ntiles, 256, 0, stream>>>(
        csc_src, csc_ec, ea, BpE, Pm, Qm, BpU, Bp2, bc2, Wc3, bc3, out, E);
}